// Round 21
// baseline (269.419 us; speedup 1.0000x reference)
//
#include <hip/hip_runtime.h>
#include <hip/hip_fp16.h>
#include <cstdint>
#include <cstddef>

// GCN fused:  out = P(P(x*(W1W2))) + (P·1)(b1ᵀW2) + 1 b2ᵀ
// P[i,j]: edge e (row=j -> col=i): dinv[j]*w[e]*dinv[i]; diag: dinv[i]^2.
// R21: R20 + reservation-based binA: per-block histogram -> one tail
//      reservation per (bucket,block) -> direct placement into block-private
//      contiguous stage ranges. No LDS edge buffer, no flush barriers.

#define TB 256
#define NBK 200     // max coarse buckets (supports N <= 102400)
#define SPLIT 4     // src-range partitions
#define GCAP 4096   // staged edges per chunk in gather (4B each -> 16KB)
#define NSL 8       // tail slots per bucket

typedef _Float16 half8 __attribute__((ext_vector_type(8)));
typedef float f32x4 __attribute__((ext_vector_type(4)));

// ---------- dtype detection: int64 edge_index has zero high words ----------
__global__ void k_detect(const unsigned* ei, int* flag) {
    int t = threadIdx.x;  // 64 threads
    unsigned v = 0;
    for (int i = t; i < 256; i += 64) v |= ei[2 * i + 1];
    unsigned long long any = __ballot(v != 0u);
    if (t == 0) *flag = (any != 0ull) ? 1 : 0;  // 1 => int32 layout, 0 => int64
}

__global__ void k_zero(int* p, int n) {
    int i = blockIdx.x * blockDim.x + threadIdx.x;
    if (i < n) p[i] = 0;
}

// ---------- pass A: reservation binning into 512-node coarse buckets ----------
__global__ __launch_bounds__(256) void k_binA(const void* __restrict__ ei,
                                              const int* __restrict__ flag,
                                              const float* __restrict__ ew,
                                              int* __restrict__ tail,
                                              int2* __restrict__ stage,
                                              int per, int E, int capx) {
    __shared__ int hist[NBK];
    __shared__ int rbase[NBK];
    __shared__ int cur[NBK];
    int t = threadIdx.x;
    int myx = blockIdx.x & (NSL - 1);
    for (int i = t; i < NBK; i += 256) { hist[i] = 0; cur[i] = 0; }
    __syncthreads();
    int s0 = blockIdx.x * per;
    int s1 = min(E, s0 + per);
    int isI32 = *flag;
    const int* p32 = (const int*)ei;
    const long long* p64 = (const long long*)ei;
    // pass 1: histogram of destination buckets
    for (int e = s0 + t; e < s1; e += 256) {
        int c = isI32 ? p32[E + e] : (int)p64[E + e];
        atomicAdd(&hist[c >> 9], 1);
    }
    __syncthreads();
    // reserve contiguous ranges in my slot
    for (int i = t; i < NBK; i += 256) {
        int h = hist[i];
        rbase[i] = h ? atomicAdd(&tail[i * NSL + myx], h) : 0;
    }
    __syncthreads();
    // pass 2: place edges into reserved (block-private) ranges
    for (int e = s0 + t; e < s1; e += 256) {
        int r, c;
        if (isI32) { r = p32[e]; c = p32[E + e]; }
        else       { r = (int)p64[e]; c = (int)p64[E + e]; }
        int bk = c >> 9;
        int pos = rbase[bk] + atomicAdd(&cur[bk], 1);
        if (pos < capx)
            stage[(size_t)(bk * NSL + myx) * capx + pos] =
                make_int2((r << 9) | (c & 511), __float_as_int(ew[e]));
    }
}

// ---------- exclusive scan of bucket totals (8 slots each) + sentinel ----------
__global__ void k_bscan(const int* __restrict__ tail, int* __restrict__ bbase,
                        int* __restrict__ ptr2, int nbk, int capx, int N) {
    __shared__ int sm[256];
    int t = threadIdx.x;
    int v = 0;
    if (t < nbk)
        for (int x = 0; x < NSL; x++) v += min(tail[t * NSL + x], capx);
    sm[t] = v;
    __syncthreads();
    for (int off = 1; off < 256; off <<= 1) {
        int add = (t >= off) ? sm[t - off] : 0;
        __syncthreads();
        sm[t] += add;
        __syncthreads();
    }
    if (t < nbk) bbase[t] = sm[t] - v;
    if (t == nbk - 1) ptr2[(size_t)N * 4] = sm[t];  // total edges staged
}

// ---------- pass B: per-bucket CSR partitioned by (node, src-range) ----------
// csr entry u32 = (src << 15) | (fp16bits(w * dinv[col]) & 0x7FFF)
__global__ __launch_bounds__(512) void k_binB(const int* __restrict__ tail,
                                              const int* __restrict__ bbase,
                                              const int2* __restrict__ stage,
                                              unsigned* __restrict__ csr,
                                              int* __restrict__ ptr2,
                                              float* __restrict__ dinv,
                                              int N, int capx, int qn) {
    __shared__ int h2[2048];      // key = (cl<<2)|rng
    __shared__ float wsm[512];    // weighted degree -> then dinv value
    __shared__ int sm[512];
    __shared__ int lpos2[2048];
    __shared__ int cseg[NSL];
    int b = blockIdx.x, t = threadIdx.x;
    for (int i = t; i < 2048; i += 512) h2[i] = 0;
    wsm[t] = 0.f;
    if (t < NSL) cseg[t] = min(tail[b * NSL + t], capx);
    __syncthreads();
#pragma unroll
    for (int x = 0; x < NSL; x++) {
        int m = cseg[x];
        size_t sb = (size_t)(b * NSL + x) * capx;
        for (int j = t; j < m; j += 512) {
            int2 v = stage[sb + j];
            int cl = v.x & 511;
            int src = v.x >> 9;
            int rng = min(src / qn, SPLIT - 1);
            atomicAdd(&h2[(cl << 2) | rng], 1);
            atomicAdd(&wsm[cl], __int_as_float(v.y));
        }
    }
    __syncthreads();
    int a0 = h2[t * 4], a1 = h2[t * 4 + 1], a2 = h2[t * 4 + 2], a3 = h2[t * 4 + 3];
    int s = a0 + a1 + a2 + a3;
    sm[t] = s;
    __syncthreads();
    for (int off = 1; off < 512; off <<= 1) {
        int add = (t >= off) ? sm[t - off] : 0;
        __syncthreads();
        sm[t] += add;
        __syncthreads();
    }
    int ex = sm[t] - s;
    int base = bbase[b];
    int node = b * 512 + t;
    int e0 = ex, e1 = ex + a0, e2 = e1 + a1, e3 = e2 + a2;
    float dv = rsqrtf(1.0f + wsm[t]);  // self-loop weight 1
    if (node < N) {
        ptr2[(size_t)node * 4 + 0] = base + e0;
        ptr2[(size_t)node * 4 + 1] = base + e1;
        ptr2[(size_t)node * 4 + 2] = base + e2;
        ptr2[(size_t)node * 4 + 3] = base + e3;
        dinv[node] = dv;
    }
    lpos2[t * 4 + 0] = e0;
    lpos2[t * 4 + 1] = e1;
    lpos2[t * 4 + 2] = e2;
    lpos2[t * 4 + 3] = e3;
    __syncthreads();
    wsm[t] = dv;  // publish dinv for placement loop
    __syncthreads();
#pragma unroll
    for (int x = 0; x < NSL; x++) {
        int m = cseg[x];
        size_t sb = (size_t)(b * NSL + x) * capx;
        for (int j = t; j < m; j += 512) {
            int2 v = stage[sb + j];
            int cl = v.x & 511;
            int src = v.x >> 9;
            int rng = min(src / qn, SPLIT - 1);
            int idx = atomicAdd(&lpos2[(cl << 2) | rng], 1);
            float wfold = __int_as_float(v.y) * wsm[cl];  // w * dinv[col] (positive)
            unsigned hb = __half_as_ushort(__float2half(wfold)) & 0x7FFFu;
            csr[base + idx] = ((unsigned)src << 15) | hb;
        }
    }
}

// ---------- fold dinv[src] into packed csr weights (one pass) ----------
__global__ void k_fold(unsigned* __restrict__ csr, const float* __restrict__ dinv,
                       const int* __restrict__ ptr2, int n4) {
    int tot = ptr2[n4];
    int j = blockIdx.x * blockDim.x + threadIdx.x;
    if (j >= tot) return;
    unsigned e = csr[j];
    unsigned r = e >> 15;
    float w = __half2float(__ushort_as_half((unsigned short)(e & 0x7FFFu)));
    float wf = w * dinv[r];
    unsigned hb = __half_as_ushort(__float2half(wf)) & 0x7FFFu;
    csr[j] = (e & ~0x7FFFu) | hb;
}

// ---------- Wc = W1@W2 -> fp16 B-fragments (MFMA order) + bw = b1@W2 ----------
__global__ void k_wc(const float* __restrict__ W1, const float* __restrict__ b1,
                     const float* __restrict__ W2, __half* __restrict__ Wcf,
                     float* __restrict__ bw) {
    __shared__ float w2s[64 * 40];
    __shared__ __half wcs[256][40];
    int t = threadIdx.x;  // 256; t = k-row of Wc
    for (int i = t; i < 64 * 40; i += 256) w2s[i] = W2[i];
    __syncthreads();
    float acc[40];
#pragma unroll
    for (int j = 0; j < 40; j++) acc[j] = 0.f;
    for (int k = 0; k < 64; k++) {
        float a = W1[t * 64 + k];
#pragma unroll
        for (int j = 0; j < 40; j++) acc[j] = fmaf(a, w2s[k * 40 + j], acc[j]);
    }
    for (int j = 0; j < 40; j++) wcs[t][j] = __float2half(acc[j]);
    if (t < 40) {
        float accb = 0.f;
        for (int k = 0; k < 64; k++) accb = fmaf(b1[k], w2s[k * 40 + t], accb);
        bw[t] = accb;
    }
    __syncthreads();
    for (int s = 0; s < 48; s++) {
        int o = t * 48 + s;
        int j = o & 7;
        int lane = (o >> 3) & 63;
        int f = o >> 9;          // 0..23
        int nt = f % 3, kt = f / 3;
        int k = kt * 32 + (lane >> 4) * 8 + j;
        int c = nt * 16 + (lane & 15);
        Wcf[o] = (c < 40) ? wcs[k][c] : __float2half(0.f);
    }
}

// ---------- Z = x @ Wc via MFMA: tile 128 rows x 48 cols, K chunked by 64 ----------
__global__ __launch_bounds__(256, 2) void k_zmm(const float* __restrict__ x,
                                                const __half* __restrict__ Wcf,
                                                __half* __restrict__ Zh, int n) {
    __shared__ __align__(16) unsigned char xs[128 * 64 * 2];  // 16 KB fp16, XOR-swizzled
    int t = threadIdx.x;
    int w = t >> 6;       // wave 0..3 -> mtiles {2w, 2w+1}
    int l = t & 63;
    int rlo = l & 15;     // A row within 16 / D col within 16
    int khi = l >> 4;     // k-group 0..3 / D row-group
    int row0 = blockIdx.x * 128;
    f32x4 acc[2][3];
#pragma unroll
    for (int m = 0; m < 2; m++)
#pragma unroll
        for (int nt = 0; nt < 3; nt++) acc[m][nt] = (f32x4){0.f, 0.f, 0.f, 0.f};

    for (int k0 = 0; k0 < 256; k0 += 64) {
        __syncthreads();
#pragma unroll
        for (int s = 0; s < 8; s++) {
            int i = t + 256 * s;          // 0..2047
            int rr = i >> 4;              // row 0..127
            int kq = (i & 15) * 4;        // k offset 0..60
            int grow = min(row0 + rr, n - 1);
            float4 v = *(const float4*)&x[(size_t)grow * 256 + k0 + kq];
            __half2 h01 = __floats2half2_rn(v.x, v.y);
            __half2 h23 = __floats2half2_rn(v.z, v.w);
            float2 pk;
            ((__half2*)&pk)[0] = h01;
            ((__half2*)&pk)[1] = h23;
            int byte = (rr * 128 + kq * 2) ^ ((rr & 7) << 4);
            *(float2*)(xs + byte) = pk;
        }
        __syncthreads();
        half8 bfr[2][3];
#pragma unroll
        for (int kt2 = 0; kt2 < 2; kt2++)
#pragma unroll
            for (int nt = 0; nt < 3; nt++) {
                int f = (k0 / 32 + kt2) * 3 + nt;
                bfr[kt2][nt] = *(const half8*)&Wcf[(size_t)(f * 64 + l) * 8];
            }
#pragma unroll
        for (int kt2 = 0; kt2 < 2; kt2++) {
#pragma unroll
            for (int m = 0; m < 2; m++) {
                int row = (w * 2 + m) * 16 + rlo;
                int byte = (row * 128 + kt2 * 64 + khi * 16) ^ ((row & 7) << 4);
                half8 af = *(const half8*)(xs + byte);
#pragma unroll
                for (int nt = 0; nt < 3; nt++)
                    acc[m][nt] = __builtin_amdgcn_mfma_f32_16x16x32_f16(af, bfr[kt2][nt], acc[m][nt], 0, 0, 0);
            }
        }
    }
#pragma unroll
    for (int m = 0; m < 2; m++) {
#pragma unroll
        for (int nt = 0; nt < 3; nt++) {
            int col = nt * 16 + rlo;
            if (col < 40) {
#pragma unroll
                for (int reg = 0; reg < 4; reg++) {
                    int grow = row0 + (w * 2 + m) * 16 + khi * 4 + reg;
                    if (grow < n) Zh[(size_t)grow * 40 + col] = __float2half(acc[m][nt][reg]);
                }
            }
        }
    }
}

// ---------- CSR gather: LDS-staged packed u32 entries, 5 lanes/node ----------
// MODE 0: dsth[i,f] = d2*src[i,f] + sum_e nv*src[r,f]           (fp16 out)
// MODE 1: out[i,f]  = same + (sw+d2)*bw[f] + b2[f]              (fp32 out)
template <int MODE>
__global__ __launch_bounds__(320) void k_gather(const int* __restrict__ ptr2,
                                                const unsigned* __restrict__ csr,
                                                const __half* __restrict__ src,
                                                const float* __restrict__ dinv,
                                                const float* __restrict__ bw,
                                                const float* __restrict__ b2,
                                                __half* __restrict__ dsth,
                                                float* __restrict__ dstf, int n) {
    __shared__ unsigned se[GCAP];  // 16 KB
    int t = threadIdx.x;       // 320 = 64 nodes * 5
    int ln = t / 5;
    int q = t - ln * 5;
    int c0 = q * 8;            // feat offset (halves)
    int n0 = blockIdx.x * 64;
    int node = n0 + ln;
    int n1 = min(n0 + 64, n);
    int st0 = ptr2[(size_t)n0 * 4];
    int en0 = ptr2[(size_t)n1 * 4];
    bool act = (node < n1);
    float d2 = 0.f;
    int st = 0, en = 0;
    float a0 = 0.f, a1 = 0.f, a2 = 0.f, a3 = 0.f, a4 = 0.f, a5 = 0.f, a6 = 0.f, a7 = 0.f;
    float sw = 0.f;
    if (act) {
        float d = dinv[node];
        d2 = d * d;
        st = ptr2[(size_t)node * 4];
        en = ptr2[(size_t)(node + 1) * 4];
        float4 raw = *(const float4*)&src[(size_t)node * 40 + c0];
        const __half2* hh = (const __half2*)&raw;
        float2 f0 = __half22float2(hh[0]), f1 = __half22float2(hh[1]);
        float2 f2 = __half22float2(hh[2]), f3 = __half22float2(hh[3]);
        a0 = d2 * f0.x; a1 = d2 * f0.y; a2 = d2 * f1.x; a3 = d2 * f1.y;
        a4 = d2 * f2.x; a5 = d2 * f2.y; a6 = d2 * f3.x; a7 = d2 * f3.y;
    }
    for (int base = st0; base < en0; base += GCAP) {
        int m = min(GCAP, en0 - base);
        __syncthreads();
        for (int i = t; i < m; i += 320) se[i] = csr[base + i];
        __syncthreads();
        if (act) {
            int lo = max(st, base) - base;
            int hi = min(en, base + m) - base;
#pragma unroll 4
            for (int j = lo; j < hi; j++) {
                unsigned e = se[j];
                float nv = __half2float(__ushort_as_half((unsigned short)(e & 0x7FFFu)));
                unsigned r = e >> 15;
                float4 raw = *(const float4*)&src[(size_t)r * 40 + c0];
                const __half2* hh = (const __half2*)&raw;
                float2 f0 = __half22float2(hh[0]), f1 = __half22float2(hh[1]);
                float2 f2 = __half22float2(hh[2]), f3 = __half22float2(hh[3]);
                if (MODE) sw += nv;
                a0 = fmaf(nv, f0.x, a0); a1 = fmaf(nv, f0.y, a1);
                a2 = fmaf(nv, f1.x, a2); a3 = fmaf(nv, f1.y, a3);
                a4 = fmaf(nv, f2.x, a4); a5 = fmaf(nv, f2.y, a5);
                a6 = fmaf(nv, f3.x, a6); a7 = fmaf(nv, f3.y, a7);
            }
        }
    }
    if (!act) return;
    if (MODE) {
        float sb = sw + d2;
        a0 += sb * bw[c0 + 0] + b2[c0 + 0];
        a1 += sb * bw[c0 + 1] + b2[c0 + 1];
        a2 += sb * bw[c0 + 2] + b2[c0 + 2];
        a3 += sb * bw[c0 + 3] + b2[c0 + 3];
        a4 += sb * bw[c0 + 4] + b2[c0 + 4];
        a5 += sb * bw[c0 + 5] + b2[c0 + 5];
        a6 += sb * bw[c0 + 6] + b2[c0 + 6];
        a7 += sb * bw[c0 + 7] + b2[c0 + 7];
        float4 o0 = make_float4(a0, a1, a2, a3);
        float4 o1 = make_float4(a4, a5, a6, a7);
        *(float4*)&dstf[(size_t)node * 40 + c0] = o0;
        *(float4*)&dstf[(size_t)node * 40 + c0 + 4] = o1;
    } else {
        float4 packed;
        ((__half2*)&packed)[0] = __floats2half2_rn(a0, a1);
        ((__half2*)&packed)[1] = __floats2half2_rn(a2, a3);
        ((__half2*)&packed)[2] = __floats2half2_rn(a4, a5);
        ((__half2*)&packed)[3] = __floats2half2_rn(a6, a7);
        *(float4*)&dsth[(size_t)node * 40 + c0] = packed;
    }
}

extern "C" void kernel_launch(void* const* d_in, const int* in_sizes, int n_in,
                              void* d_out, int out_size, void* d_ws, size_t ws_size,
                              hipStream_t stream) {
    const float* x  = (const float*)d_in[0];
    const void*  ei = d_in[1];
    const float* ew = (const float*)d_in[2];
    const float* W1 = (const float*)d_in[3];
    const float* b1 = (const float*)d_in[4];
    const float* W2 = (const float*)d_in[5];
    const float* b2 = (const float*)d_in[6];
    float* out = (float*)d_out;

    const int E = in_sizes[1] / 2;        // 3,200,000
    const int N = in_sizes[0] / 256;      // 100,000
    const int nbk = (N + 511) >> 9;       // 196 coarse buckets (<= NBK)
    const int capx = E / (nbk * NSL) + 768;  // per-(bucket,slot) capacity ~2808
    const int qn = (N + SPLIT - 1) / SPLIT;

    char* ws = (char*)d_ws;
    float*  dinv = (float*)(ws + 0);                       // N f
    int*    flag = (int*)(ws + (1u << 19));
    float*  bw   = (float*)(ws + (1u << 19) + 256);
    __half* Wcf  = (__half*)(ws + (1u << 19) + 4096);      // 12288 halves = 24KB
    int*    tail = (int*)(ws + (1u << 19) + 65536);        // NBK*NSL ints
    int*    bbase = (int*)(ws + (1u << 19) + 65536 + 16384);
    size_t off = (size_t)1 << 20;
    size_t estride = ((size_t)E * 4 + 255) & ~(size_t)255;
    size_t n4stride = ((size_t)(N * 4 + 1) * 4 + 255) & ~(size_t)255;
    size_t hstride = ((size_t)N * 40 * 2 + 255) & ~(size_t)255;
    int*      ptr2 = (int*)(ws + off);      off += n4stride;                  // 1.6MB
    unsigned* csr  = (unsigned*)(ws + off); off += estride;                   // E*4B
    int2*     stage = (int2*)(ws + off);    off += (size_t)NBK * NSL * capx * 8;  // ~36MB
    __half*   Zh   = (__half*)(ws + off);   off += hstride;                   // 8MB
    __half*   T1h  = (__half*)(ws + off);                                     // 8MB

    const int NB = 1024;                  // binA blocks (128 per slot id)
    const int per = (E + NB - 1) / NB;    // ~3125 edges/block
    int gb = (N + 63) / 64;

    k_detect<<<1, 64, 0, stream>>>((const unsigned*)ei, flag);
    k_zero<<<(NBK * NSL + TB - 1) / TB, TB, 0, stream>>>(tail, NBK * NSL);
    k_binA<<<NB, 256, 0, stream>>>(ei, flag, ew, tail, stage, per, E, capx);
    k_bscan<<<1, 256, 0, stream>>>(tail, bbase, ptr2, nbk, capx, N);
    k_binB<<<nbk, 512, 0, stream>>>(tail, bbase, stage, csr, ptr2, dinv, N, capx, qn);
    k_fold<<<(E + TB - 1) / TB, TB, 0, stream>>>(csr, dinv, ptr2, N * 4);
    k_wc<<<1, TB, 0, stream>>>(W1, b1, W2, Wcf, bw);
    k_zmm<<<(N + 127) / 128, TB, 0, stream>>>(x, Wcf, Zh, N);
    k_gather<0><<<gb, 320, 0, stream>>>(ptr2, csr, Zh, dinv, bw, b2, T1h, nullptr, N);
    k_gather<1><<<gb, 320, 0, stream>>>(ptr2, csr, T1h, dinv, bw, b2, nullptr, out, N);
}

// Round 22
// 262.468 us; speedup vs baseline: 1.0265x; 1.0265x over previous
//
#include <hip/hip_runtime.h>
#include <hip/hip_fp16.h>
#include <cstdint>
#include <cstddef>

// GCN fused:  out = P(P(x*(W1W2))) + (P·1)(b1ᵀW2) + 1 b2ᵀ
// P[i,j]: edge e (row=j -> col=i): dinv[j]*w[e]*dinv[i]; diag: dinv[i]^2.
// R22: revert binA to R20's LDS-multisplit flush version (best measured);
//      keep packed 4B CSR and all else from R20. (R21's reservation binA
//      regressed: scattered 8B writes across 196 regions/wave.)

#define TB 256
#define NBK 200     // max coarse buckets (supports N <= 102400)
#define LCAP 32     // LDS entries per bucket
#define SPLIT 4     // src-range partitions
#define GCAP 4096   // staged edges per chunk in gather (4B each -> 16KB)
#define NSL 8       // tail slots per bucket

typedef _Float16 half8 __attribute__((ext_vector_type(8)));
typedef float f32x4 __attribute__((ext_vector_type(4)));

// ---------- dtype detection: int64 edge_index has zero high words ----------
__global__ void k_detect(const unsigned* ei, int* flag) {
    int t = threadIdx.x;  // 64 threads
    unsigned v = 0;
    for (int i = t; i < 256; i += 64) v |= ei[2 * i + 1];
    unsigned long long any = __ballot(v != 0u);
    if (t == 0) *flag = (any != 0ull) ? 1 : 0;  // 1 => int32 layout, 0 => int64
}

__global__ void k_zero(int* p, int n) {
    int i = blockIdx.x * blockDim.x + threadIdx.x;
    if (i < n) p[i] = 0;
}

// ---------- pass A: LDS multisplit into 512-node coarse buckets, 8-way slots ----------
__global__ __launch_bounds__(256) void k_binA(const void* __restrict__ ei,
                                              const int* __restrict__ flag,
                                              const float* __restrict__ ew,
                                              int* __restrict__ tail,
                                              int2* __restrict__ stage,
                                              int per, int E, int capx) {
    __shared__ int2 lbuf[NBK][LCAP];  // 51200 B
    __shared__ int lcnt[NBK];
    int t = threadIdx.x;
    int myx = blockIdx.x & (NSL - 1);
    for (int i = t; i < NBK; i += 256) lcnt[i] = 0;
    __syncthreads();
    int s0 = blockIdx.x * per;
    int s1 = min(E, s0 + per);
    int isI32 = *flag;
    const int* p32 = (const int*)ei;
    const long long* p64 = (const long long*)ei;
    for (int b0 = s0; b0 < s1; b0 += 2048) {
        int2 ent[8];
        int bk[8];
#pragma unroll
        for (int u = 0; u < 8; u++) {
            int e = b0 + u * 256 + t;
            bk[u] = -1;
            if (e < s1) {
                int r, c;
                if (isI32) { r = p32[e]; c = p32[E + e]; }
                else       { r = (int)p64[e]; c = (int)p64[E + e]; }
                bk[u] = c >> 9;
                ent[u] = make_int2((r << 9) | (c & 511), __float_as_int(ew[e]));
            }
        }
#pragma unroll
        for (int u = 0; u < 8; u++) {
            if (bk[u] < 0) continue;
            int pos = atomicAdd(&lcnt[bk[u]], 1);
            if (pos < LCAP) {
                lbuf[bk[u]][pos] = ent[u];
            } else {  // rare spill: direct global append to my slot
                int slot = bk[u] * NSL + myx;
                int g = atomicAdd(&tail[slot], 1);
                if (g < capx) stage[(size_t)slot * capx + g] = ent[u];
            }
        }
        __syncthreads();
        if (t < NBK) {
            int c = min(lcnt[t], LCAP);
            int n16 = c & ~15;
            if (n16) {
                int slot = t * NSL + myx;
                int base = atomicAdd(&tail[slot], n16);
                size_t db = (size_t)slot * capx;
                for (int j = 0; j < n16; j++) {
                    int g = base + j;
                    if (g < capx) stage[db + g] = lbuf[t][j];
                }
                int rem = c - n16;
                for (int j = 0; j < rem; j++) lbuf[t][j] = lbuf[t][n16 + j];
                lcnt[t] = rem;
            } else {
                lcnt[t] = c;
            }
        }
        __syncthreads();
    }
    if (t < NBK) {
        int c = min(lcnt[t], LCAP);
        if (c) {
            int slot = t * NSL + myx;
            int base = atomicAdd(&tail[slot], c);
            size_t db = (size_t)slot * capx;
            for (int j = 0; j < c; j++) {
                int g = base + j;
                if (g < capx) stage[db + g] = lbuf[t][j];
            }
        }
    }
}

// ---------- exclusive scan of bucket totals (8 slots each) + sentinel ----------
__global__ void k_bscan(const int* __restrict__ tail, int* __restrict__ bbase,
                        int* __restrict__ ptr2, int nbk, int capx, int N) {
    __shared__ int sm[256];
    int t = threadIdx.x;
    int v = 0;
    if (t < nbk)
        for (int x = 0; x < NSL; x++) v += min(tail[t * NSL + x], capx);
    sm[t] = v;
    __syncthreads();
    for (int off = 1; off < 256; off <<= 1) {
        int add = (t >= off) ? sm[t - off] : 0;
        __syncthreads();
        sm[t] += add;
        __syncthreads();
    }
    if (t < nbk) bbase[t] = sm[t] - v;
    if (t == nbk - 1) ptr2[(size_t)N * 4] = sm[t];  // total edges staged
}

// ---------- pass B: per-bucket CSR partitioned by (node, src-range) ----------
// csr entry u32 = (src << 15) | (fp16bits(w * dinv[col]) & 0x7FFF)
__global__ __launch_bounds__(512) void k_binB(const int* __restrict__ tail,
                                              const int* __restrict__ bbase,
                                              const int2* __restrict__ stage,
                                              unsigned* __restrict__ csr,
                                              int* __restrict__ ptr2,
                                              float* __restrict__ dinv,
                                              int N, int capx, int qn) {
    __shared__ int h2[2048];      // key = (cl<<2)|rng
    __shared__ float wsm[512];    // weighted degree -> then dinv value
    __shared__ int sm[512];
    __shared__ int lpos2[2048];
    __shared__ int cseg[NSL];
    int b = blockIdx.x, t = threadIdx.x;
    for (int i = t; i < 2048; i += 512) h2[i] = 0;
    wsm[t] = 0.f;
    if (t < NSL) cseg[t] = min(tail[b * NSL + t], capx);
    __syncthreads();
#pragma unroll
    for (int x = 0; x < NSL; x++) {
        int m = cseg[x];
        size_t sb = (size_t)(b * NSL + x) * capx;
        for (int j = t; j < m; j += 512) {
            int2 v = stage[sb + j];
            int cl = v.x & 511;
            int src = v.x >> 9;
            int rng = min(src / qn, SPLIT - 1);
            atomicAdd(&h2[(cl << 2) | rng], 1);
            atomicAdd(&wsm[cl], __int_as_float(v.y));
        }
    }
    __syncthreads();
    int a0 = h2[t * 4], a1 = h2[t * 4 + 1], a2 = h2[t * 4 + 2], a3 = h2[t * 4 + 3];
    int s = a0 + a1 + a2 + a3;
    sm[t] = s;
    __syncthreads();
    for (int off = 1; off < 512; off <<= 1) {
        int add = (t >= off) ? sm[t - off] : 0;
        __syncthreads();
        sm[t] += add;
        __syncthreads();
    }
    int ex = sm[t] - s;
    int base = bbase[b];
    int node = b * 512 + t;
    int e0 = ex, e1 = ex + a0, e2 = e1 + a1, e3 = e2 + a2;
    float dv = rsqrtf(1.0f + wsm[t]);  // self-loop weight 1
    if (node < N) {
        ptr2[(size_t)node * 4 + 0] = base + e0;
        ptr2[(size_t)node * 4 + 1] = base + e1;
        ptr2[(size_t)node * 4 + 2] = base + e2;
        ptr2[(size_t)node * 4 + 3] = base + e3;
        dinv[node] = dv;
    }
    lpos2[t * 4 + 0] = e0;
    lpos2[t * 4 + 1] = e1;
    lpos2[t * 4 + 2] = e2;
    lpos2[t * 4 + 3] = e3;
    __syncthreads();
    wsm[t] = dv;  // publish dinv for placement loop
    __syncthreads();
#pragma unroll
    for (int x = 0; x < NSL; x++) {
        int m = cseg[x];
        size_t sb = (size_t)(b * NSL + x) * capx;
        for (int j = t; j < m; j += 512) {
            int2 v = stage[sb + j];
            int cl = v.x & 511;
            int src = v.x >> 9;
            int rng = min(src / qn, SPLIT - 1);
            int idx = atomicAdd(&lpos2[(cl << 2) | rng], 1);
            float wfold = __int_as_float(v.y) * wsm[cl];  // w * dinv[col] (positive)
            unsigned hb = __half_as_ushort(__float2half(wfold)) & 0x7FFFu;
            csr[base + idx] = ((unsigned)src << 15) | hb;
        }
    }
}

// ---------- fold dinv[src] into packed csr weights (one pass) ----------
__global__ void k_fold(unsigned* __restrict__ csr, const float* __restrict__ dinv,
                       const int* __restrict__ ptr2, int n4) {
    int tot = ptr2[n4];
    int j = blockIdx.x * blockDim.x + threadIdx.x;
    if (j >= tot) return;
    unsigned e = csr[j];
    unsigned r = e >> 15;
    float w = __half2float(__ushort_as_half((unsigned short)(e & 0x7FFFu)));
    float wf = w * dinv[r];
    unsigned hb = __half_as_ushort(__float2half(wf)) & 0x7FFFu;
    csr[j] = (e & ~0x7FFFu) | hb;
}

// ---------- Wc = W1@W2 -> fp16 B-fragments (MFMA order) + bw = b1@W2 ----------
__global__ void k_wc(const float* __restrict__ W1, const float* __restrict__ b1,
                     const float* __restrict__ W2, __half* __restrict__ Wcf,
                     float* __restrict__ bw) {
    __shared__ float w2s[64 * 40];
    __shared__ __half wcs[256][40];
    int t = threadIdx.x;  // 256; t = k-row of Wc
    for (int i = t; i < 64 * 40; i += 256) w2s[i] = W2[i];
    __syncthreads();
    float acc[40];
#pragma unroll
    for (int j = 0; j < 40; j++) acc[j] = 0.f;
    for (int k = 0; k < 64; k++) {
        float a = W1[t * 64 + k];
#pragma unroll
        for (int j = 0; j < 40; j++) acc[j] = fmaf(a, w2s[k * 40 + j], acc[j]);
    }
    for (int j = 0; j < 40; j++) wcs[t][j] = __float2half(acc[j]);
    if (t < 40) {
        float accb = 0.f;
        for (int k = 0; k < 64; k++) accb = fmaf(b1[k], w2s[k * 40 + t], accb);
        bw[t] = accb;
    }
    __syncthreads();
    for (int s = 0; s < 48; s++) {
        int o = t * 48 + s;
        int j = o & 7;
        int lane = (o >> 3) & 63;
        int f = o >> 9;          // 0..23
        int nt = f % 3, kt = f / 3;
        int k = kt * 32 + (lane >> 4) * 8 + j;
        int c = nt * 16 + (lane & 15);
        Wcf[o] = (c < 40) ? wcs[k][c] : __float2half(0.f);
    }
}

// ---------- Z = x @ Wc via MFMA: tile 128 rows x 48 cols, K chunked by 64 ----------
__global__ __launch_bounds__(256, 2) void k_zmm(const float* __restrict__ x,
                                                const __half* __restrict__ Wcf,
                                                __half* __restrict__ Zh, int n) {
    __shared__ __align__(16) unsigned char xs[128 * 64 * 2];  // 16 KB fp16, XOR-swizzled
    int t = threadIdx.x;
    int w = t >> 6;       // wave 0..3 -> mtiles {2w, 2w+1}
    int l = t & 63;
    int rlo = l & 15;     // A row within 16 / D col within 16
    int khi = l >> 4;     // k-group 0..3 / D row-group
    int row0 = blockIdx.x * 128;
    f32x4 acc[2][3];
#pragma unroll
    for (int m = 0; m < 2; m++)
#pragma unroll
        for (int nt = 0; nt < 3; nt++) acc[m][nt] = (f32x4){0.f, 0.f, 0.f, 0.f};

    for (int k0 = 0; k0 < 256; k0 += 64) {
        __syncthreads();
#pragma unroll
        for (int s = 0; s < 8; s++) {
            int i = t + 256 * s;          // 0..2047
            int rr = i >> 4;              // row 0..127
            int kq = (i & 15) * 4;        // k offset 0..60
            int grow = min(row0 + rr, n - 1);
            float4 v = *(const float4*)&x[(size_t)grow * 256 + k0 + kq];
            __half2 h01 = __floats2half2_rn(v.x, v.y);
            __half2 h23 = __floats2half2_rn(v.z, v.w);
            float2 pk;
            ((__half2*)&pk)[0] = h01;
            ((__half2*)&pk)[1] = h23;
            int byte = (rr * 128 + kq * 2) ^ ((rr & 7) << 4);
            *(float2*)(xs + byte) = pk;
        }
        __syncthreads();
        half8 bfr[2][3];
#pragma unroll
        for (int kt2 = 0; kt2 < 2; kt2++)
#pragma unroll
            for (int nt = 0; nt < 3; nt++) {
                int f = (k0 / 32 + kt2) * 3 + nt;
                bfr[kt2][nt] = *(const half8*)&Wcf[(size_t)(f * 64 + l) * 8];
            }
#pragma unroll
        for (int kt2 = 0; kt2 < 2; kt2++) {
#pragma unroll
            for (int m = 0; m < 2; m++) {
                int row = (w * 2 + m) * 16 + rlo;
                int byte = (row * 128 + kt2 * 64 + khi * 16) ^ ((row & 7) << 4);
                half8 af = *(const half8*)(xs + byte);
#pragma unroll
                for (int nt = 0; nt < 3; nt++)
                    acc[m][nt] = __builtin_amdgcn_mfma_f32_16x16x32_f16(af, bfr[kt2][nt], acc[m][nt], 0, 0, 0);
            }
        }
    }
#pragma unroll
    for (int m = 0; m < 2; m++) {
#pragma unroll
        for (int nt = 0; nt < 3; nt++) {
            int col = nt * 16 + rlo;
            if (col < 40) {
#pragma unroll
                for (int reg = 0; reg < 4; reg++) {
                    int grow = row0 + (w * 2 + m) * 16 + khi * 4 + reg;
                    if (grow < n) Zh[(size_t)grow * 40 + col] = __float2half(acc[m][nt][reg]);
                }
            }
        }
    }
}

// ---------- CSR gather: LDS-staged packed u32 entries, 5 lanes/node ----------
// MODE 0: dsth[i,f] = d2*src[i,f] + sum_e nv*src[r,f]           (fp16 out)
// MODE 1: out[i,f]  = same + (sw+d2)*bw[f] + b2[f]              (fp32 out)
template <int MODE>
__global__ __launch_bounds__(320) void k_gather(const int* __restrict__ ptr2,
                                                const unsigned* __restrict__ csr,
                                                const __half* __restrict__ src,
                                                const float* __restrict__ dinv,
                                                const float* __restrict__ bw,
                                                const float* __restrict__ b2,
                                                __half* __restrict__ dsth,
                                                float* __restrict__ dstf, int n) {
    __shared__ unsigned se[GCAP];  // 16 KB
    int t = threadIdx.x;       // 320 = 64 nodes * 5
    int ln = t / 5;
    int q = t - ln * 5;
    int c0 = q * 8;            // feat offset (halves)
    int n0 = blockIdx.x * 64;
    int node = n0 + ln;
    int n1 = min(n0 + 64, n);
    int st0 = ptr2[(size_t)n0 * 4];
    int en0 = ptr2[(size_t)n1 * 4];
    bool act = (node < n1);
    float d2 = 0.f;
    int st = 0, en = 0;
    float a0 = 0.f, a1 = 0.f, a2 = 0.f, a3 = 0.f, a4 = 0.f, a5 = 0.f, a6 = 0.f, a7 = 0.f;
    float sw = 0.f;
    if (act) {
        float d = dinv[node];
        d2 = d * d;
        st = ptr2[(size_t)node * 4];
        en = ptr2[(size_t)(node + 1) * 4];
        float4 raw = *(const float4*)&src[(size_t)node * 40 + c0];
        const __half2* hh = (const __half2*)&raw;
        float2 f0 = __half22float2(hh[0]), f1 = __half22float2(hh[1]);
        float2 f2 = __half22float2(hh[2]), f3 = __half22float2(hh[3]);
        a0 = d2 * f0.x; a1 = d2 * f0.y; a2 = d2 * f1.x; a3 = d2 * f1.y;
        a4 = d2 * f2.x; a5 = d2 * f2.y; a6 = d2 * f3.x; a7 = d2 * f3.y;
    }
    for (int base = st0; base < en0; base += GCAP) {
        int m = min(GCAP, en0 - base);
        __syncthreads();
        for (int i = t; i < m; i += 320) se[i] = csr[base + i];
        __syncthreads();
        if (act) {
            int lo = max(st, base) - base;
            int hi = min(en, base + m) - base;
#pragma unroll 4
            for (int j = lo; j < hi; j++) {
                unsigned e = se[j];
                float nv = __half2float(__ushort_as_half((unsigned short)(e & 0x7FFFu)));
                unsigned r = e >> 15;
                float4 raw = *(const float4*)&src[(size_t)r * 40 + c0];
                const __half2* hh = (const __half2*)&raw;
                float2 f0 = __half22float2(hh[0]), f1 = __half22float2(hh[1]);
                float2 f2 = __half22float2(hh[2]), f3 = __half22float2(hh[3]);
                if (MODE) sw += nv;
                a0 = fmaf(nv, f0.x, a0); a1 = fmaf(nv, f0.y, a1);
                a2 = fmaf(nv, f1.x, a2); a3 = fmaf(nv, f1.y, a3);
                a4 = fmaf(nv, f2.x, a4); a5 = fmaf(nv, f2.y, a5);
                a6 = fmaf(nv, f3.x, a6); a7 = fmaf(nv, f3.y, a7);
            }
        }
    }
    if (!act) return;
    if (MODE) {
        float sb = sw + d2;
        a0 += sb * bw[c0 + 0] + b2[c0 + 0];
        a1 += sb * bw[c0 + 1] + b2[c0 + 1];
        a2 += sb * bw[c0 + 2] + b2[c0 + 2];
        a3 += sb * bw[c0 + 3] + b2[c0 + 3];
        a4 += sb * bw[c0 + 4] + b2[c0 + 4];
        a5 += sb * bw[c0 + 5] + b2[c0 + 5];
        a6 += sb * bw[c0 + 6] + b2[c0 + 6];
        a7 += sb * bw[c0 + 7] + b2[c0 + 7];
        float4 o0 = make_float4(a0, a1, a2, a3);
        float4 o1 = make_float4(a4, a5, a6, a7);
        *(float4*)&dstf[(size_t)node * 40 + c0] = o0;
        *(float4*)&dstf[(size_t)node * 40 + c0 + 4] = o1;
    } else {
        float4 packed;
        ((__half2*)&packed)[0] = __floats2half2_rn(a0, a1);
        ((__half2*)&packed)[1] = __floats2half2_rn(a2, a3);
        ((__half2*)&packed)[2] = __floats2half2_rn(a4, a5);
        ((__half2*)&packed)[3] = __floats2half2_rn(a6, a7);
        *(float4*)&dsth[(size_t)node * 40 + c0] = packed;
    }
}

extern "C" void kernel_launch(void* const* d_in, const int* in_sizes, int n_in,
                              void* d_out, int out_size, void* d_ws, size_t ws_size,
                              hipStream_t stream) {
    const float* x  = (const float*)d_in[0];
    const void*  ei = d_in[1];
    const float* ew = (const float*)d_in[2];
    const float* W1 = (const float*)d_in[3];
    const float* b1 = (const float*)d_in[4];
    const float* W2 = (const float*)d_in[5];
    const float* b2 = (const float*)d_in[6];
    float* out = (float*)d_out;

    const int E = in_sizes[1] / 2;        // 3,200,000
    const int N = in_sizes[0] / 256;      // 100,000
    const int nbk = (N + 511) >> 9;       // 196 coarse buckets (<= NBK)
    const int capx = E / (nbk * NSL) + 768;  // per-(bucket,slot) capacity ~2808
    const int qn = (N + SPLIT - 1) / SPLIT;

    char* ws = (char*)d_ws;
    float*  dinv = (float*)(ws + 0);                       // N f
    int*    flag = (int*)(ws + (1u << 19));
    float*  bw   = (float*)(ws + (1u << 19) + 256);
    __half* Wcf  = (__half*)(ws + (1u << 19) + 4096);      // 12288 halves = 24KB
    int*    tail = (int*)(ws + (1u << 19) + 65536);        // NBK*NSL ints
    int*    bbase = (int*)(ws + (1u << 19) + 65536 + 16384);
    size_t off = (size_t)1 << 20;
    size_t estride = ((size_t)E * 4 + 255) & ~(size_t)255;
    size_t n4stride = ((size_t)(N * 4 + 1) * 4 + 255) & ~(size_t)255;
    size_t hstride = ((size_t)N * 40 * 2 + 255) & ~(size_t)255;
    int*      ptr2 = (int*)(ws + off);      off += n4stride;                  // 1.6MB
    unsigned* csr  = (unsigned*)(ws + off); off += estride;                   // E*4B
    int2*     stage = (int2*)(ws + off);    off += (size_t)NBK * NSL * capx * 8;  // ~36MB
    __half*   Zh   = (__half*)(ws + off);   off += hstride;                   // 8MB
    __half*   T1h  = (__half*)(ws + off);                                     // 8MB

    const int NB = 608;                   // binA blocks (76 per slot id)
    const int per = (E + NB - 1) / NB;
    int gb = (N + 63) / 64;

    k_detect<<<1, 64, 0, stream>>>((const unsigned*)ei, flag);
    k_zero<<<(NBK * NSL + TB - 1) / TB, TB, 0, stream>>>(tail, NBK * NSL);
    k_binA<<<NB, 256, 0, stream>>>(ei, flag, ew, tail, stage, per, E, capx);
    k_bscan<<<1, 256, 0, stream>>>(tail, bbase, ptr2, nbk, capx, N);
    k_binB<<<nbk, 512, 0, stream>>>(tail, bbase, stage, csr, ptr2, dinv, N, capx, qn);
    k_fold<<<(E + TB - 1) / TB, TB, 0, stream>>>(csr, dinv, ptr2, N * 4);
    k_wc<<<1, TB, 0, stream>>>(W1, b1, W2, Wcf, bw);
    k_zmm<<<(N + 127) / 128, TB, 0, stream>>>(x, Wcf, Zh, N);
    k_gather<0><<<gb, 320, 0, stream>>>(ptr2, csr, Zh, dinv, bw, b2, T1h, nullptr, N);
    k_gather<1><<<gb, 320, 0, stream>>>(ptr2, csr, T1h, dinv, bw, b2, nullptr, out, N);
}